// Round 15
// baseline (336.699 us; speedup 1.0000x reference)
//
#include <hip/hip_runtime.h>
#include <hip/hip_bf16.h>
#include <cstdint>
#include <cstddef>

// Problem shape (fixed): x [B=16][N=2048][D=512] fp32
#define BB 16
#define NN 2048
#define DD 512

typedef _Float16 f16x8 __attribute__((ext_vector_type(8)));
typedef _Float16 f16x4 __attribute__((ext_vector_type(4)));
typedef float f32x4 __attribute__((ext_vector_type(4)));
typedef unsigned int u32x4 __attribute__((ext_vector_type(4)));

// Async global->LDS, 16 B per lane. LDS dest = wave-uniform base + lane*16.
__device__ __forceinline__ void async_ld16(void* lds, const void* g) {
    __builtin_amdgcn_global_load_lds(
        (const __attribute__((address_space(1))) unsigned int*)(uintptr_t)g,
        (__attribute__((address_space(3))) unsigned int*)(uint32_t)(uintptr_t)lds,
        16, 0, 0);
}

#define VM_WAIT(n) asm volatile("s_waitcnt vmcnt(" #n ")" ::: "memory")
#define RAW_BAR()  do { asm volatile("" ::: "memory"); __builtin_amdgcn_s_barrier(); asm volatile("" ::: "memory"); } while (0)
// LDS-order-only barrier: global stores/atomics keep draining.
#define LGKM_BAR() do { asm volatile("s_waitcnt lgkmcnt(0)" ::: "memory"); \
                        __builtin_amdgcn_s_barrier();                      \
                        __builtin_amdgcn_sched_barrier(0); } while (0)

// ---------------------------------------------------------------------------
// K1 (fused): read x ONCE (non-temporal: stream-once). Per 64-row slab:
// norms, xhn (normalized fp16), vT (fp16 transpose), denom zero-init.
// grid (NN/64, BB), 256 threads.
// ---------------------------------------------------------------------------
__global__ __launch_bounds__(256) void k_prep(const float* __restrict__ x,
                                              _Float16* __restrict__ xhn,
                                              _Float16* __restrict__ vT,
                                              float* __restrict__ denom) {
    __shared__ _Float16 t[512 * 66];     // [d][j], pitch 66 halves
    const int tid = threadIdx.x, lane = tid & 63, w = tid >> 6;
    const int b = blockIdx.y, j0 = blockIdx.x * 64;
    if (tid < 64) denom[b * NN + j0 + tid] = 0.f;
    const float* xb = x + ((size_t)b * NN + j0) * DD;

    for (int rr = 0; rr < 16; ++rr) {
        const int jj = w * 16 + rr;                 // row within slab
        const float* xr = xb + (size_t)jj * DD;
        f32x4 a = __builtin_nontemporal_load((const f32x4*)xr + lane);
        f32x4 c = __builtin_nontemporal_load((const f32x4*)xr + lane + 64);
        float ss = a[0]*a[0] + a[1]*a[1] + a[2]*a[2] + a[3]*a[3]
                 + c[0]*c[0] + c[1]*c[1] + c[2]*c[2] + c[3]*c[3];
        #pragma unroll
        for (int o = 1; o < 64; o <<= 1) ss += __shfl_xor(ss, o);
        const float rn = 1.0f / sqrtf(ss);
        // normalized fp16 row (coalesced 8B stores)
        _Float16* dst = xhn + ((size_t)b * NN + j0 + jj) * DD;
        f16x4 v0 = {(_Float16)(a[0]*rn), (_Float16)(a[1]*rn), (_Float16)(a[2]*rn), (_Float16)(a[3]*rn)};
        f16x4 v1 = {(_Float16)(c[0]*rn), (_Float16)(c[1]*rn), (_Float16)(c[2]*rn), (_Float16)(c[3]*rn)};
        *(f16x4*)(dst + 4 * lane) = v0;
        *(f16x4*)(dst + 256 + 4 * lane) = v1;
        // unnormalized fp16 into transposed LDS tile
        const int d0 = 4 * lane, d1 = 256 + 4 * lane;
        t[(d0 + 0) * 66 + jj] = (_Float16)a[0];
        t[(d0 + 1) * 66 + jj] = (_Float16)a[1];
        t[(d0 + 2) * 66 + jj] = (_Float16)a[2];
        t[(d0 + 3) * 66 + jj] = (_Float16)a[3];
        t[(d1 + 0) * 66 + jj] = (_Float16)c[0];
        t[(d1 + 1) * 66 + jj] = (_Float16)c[1];
        t[(d1 + 2) * 66 + jj] = (_Float16)c[2];
        t[(d1 + 3) * 66 + jj] = (_Float16)c[3];
    }
    LGKM_BAR();   // xhn global stores keep draining under the vT phase
    // store vT rows: 512 d x 8 chunks of 8 halves; 4B-aligned b32 LDS reads.
    #pragma unroll
    for (int it = 0; it < 16; ++it) {
        const int id = it * 256 + tid;
        const int d = id >> 3, ch = (id & 7) * 8;
        const uint32_t* tp = (const uint32_t*)&t[d * 66 + ch];
        uint4 v = {tp[0], tp[1], tp[2], tp[3]};
        *(uint4*)(vT + ((size_t)b * DD + d) * NN + j0 + ch) = v;
    }
}

// ---------------------------------------------------------------------------
// K2: W = exp( xhn xhn^T ), symmetric-triangular. 128x128 block, 4 waves,
// single-buffered BK=64, XCD tile-pair swizzle, lane-coalesced stores,
// stores-before-atomics ordering, LGKM-only barriers.
// NEW this round: epilogue transposes in TWO 64-wide passes (scratch
// 64x136 = 17.4 KB, inside the 32 KB GEMM buffers) -> declared LDS exactly
// 32768 B -> 5 blocks/CU (was 4). Same transformation as R7's win: more
// desynced blocks per CU to TLP-cover the VM_WAIT(0) + store drain.
// ---------------------------------------------------------------------------
__global__ __launch_bounds__(256, 5) void k_scores(const _Float16* __restrict__ xhn,
                                                   _Float16* __restrict__ W,
                                                   float* __restrict__ denom) {
    __shared__ _Float16 smem[16384];          // As[8192]+Bs[8192] = 32768 B
    const int tid = threadIdx.x;
    const int lane = tid & 63, wv = tid >> 6;
    const int wr = wv >> 1, wc = wv & 1;
    const int m_ = lane & 15, quad = lane >> 4;
    const int b = blockIdx.z;

    // XCD swizzle: 136 = 8 * 17 -> each XCD gets 17 consecutive pairs.
    const int swz = (blockIdx.x % 8) * 17 + blockIdx.x / 8;
    int rem = swz, ti = 0, rowlen = NN / 128;
    while (rem >= rowlen) { rem -= rowlen; ++ti; --rowlen; }
    const int tj = ti + rem;
    const int I = ti * 128, J = tj * 128;
    const bool diag = (ti == tj);

    const _Float16* Ab = xhn + ((size_t)b * NN + I) * DD;
    const _Float16* Bb = xhn + ((size_t)b * NN + J) * DD;

    f32x4 acc[4][4];
    #pragma unroll
    for (int i = 0; i < 4; ++i)
        #pragma unroll
        for (int j = 0; j < 4; ++j) acc[i][j] = (f32x4){0.f, 0.f, 0.f, 0.f};

    const int sub = lane >> 3;
    const int swc = (lane & 7) ^ sub;
    const _Float16* agl = Ab + (size_t)(wv * 32 + sub) * DD + swc * 8;
    const _Float16* bgl = Bb + (size_t)(wv * 32 + sub) * DD + swc * 8;
    _Float16* As = smem;
    _Float16* Bs = smem + 8192;

    for (int kb = 0; kb < DD / 64; ++kb) {
        const int k0 = kb * 64;
        #pragma unroll
        for (int c = 0; c < 4; ++c) {
            async_ld16(&As[(wv * 32 + c * 8) * 64], agl + (size_t)c * 8 * DD + k0);
            async_ld16(&Bs[(wv * 32 + c * 8) * 64], bgl + (size_t)c * 8 * DD + k0);
        }
        VM_WAIT(0);
        RAW_BAR();
        __builtin_amdgcn_s_setprio(1);
        #pragma unroll
        for (int kc = 0; kc < 2; ++kc) {
            f16x8 af[4], bf[4];
            #pragma unroll
            for (int t = 0; t < 4; ++t) {
                const int Ra = wr * 64 + t * 16 + m_;
                const int Rb = wc * 64 + t * 16 + m_;
                af[t] = *(const f16x8*)&As[Ra * 64 + (((kc * 4 + quad) ^ (Ra & 7)) * 8)];
                bf[t] = *(const f16x8*)&Bs[Rb * 64 + (((kc * 4 + quad) ^ (Rb & 7)) * 8)];
            }
            #pragma unroll
            for (int i = 0; i < 4; ++i)
                #pragma unroll
                for (int j = 0; j < 4; ++j)
                    acc[i][j] = __builtin_amdgcn_mfma_f32_16x16x32_f16(af[i], bf[j], acc[i][j], 0, 0, 0);
        }
        __builtin_amdgcn_s_setprio(0);
        RAW_BAR();   // all waves done reading before next stage overwrites
    }

    // Epilogue: exp into packed f16x4; register row/col partial sums.
    f16x4 wq[4][4];
    float rowpart[4][4];
    float colpart[4] = {0.f, 0.f, 0.f, 0.f};
    #pragma unroll
    for (int i = 0; i < 4; ++i)
        #pragma unroll
        for (int r = 0; r < 4; ++r) rowpart[i][r] = 0.f;

    #pragma unroll
    for (int i = 0; i < 4; ++i) {
        #pragma unroll
        for (int j = 0; j < 4; ++j) {
            #pragma unroll
            for (int r = 0; r < 4; ++r) {
                const float w = __expf(acc[i][j][r]);
                wq[i][j][r] = (_Float16)w;
                rowpart[i][r] += w;
                colpart[j] += w;
            }
        }
    }

    // ---- Phase 1: W(J,I) via [scol][srow] transpose, two 64-col passes ----
    // scratch: 64 cols x 136 row-pitch = 17408 B, overlaying GEMM buffers.
    _Float16* WtT = smem;
    #pragma unroll
    for (int s = 0; s < 2; ++s) {
        if (wc == s) {       // waves owning scols [s*64, s*64+64)
            #pragma unroll
            for (int i = 0; i < 4; ++i) {
                const int rowb = wr * 64 + i * 16 + quad * 4;
                #pragma unroll
                for (int j = 0; j < 4; ++j) {
                    const int lsc = j * 16 + m_;      // scol - s*64
                    *(f16x4*)&WtT[lsc * 136 + rowb] = wq[i][j];
                }
            }
        }
        LGKM_BAR();
        // lane-coalesced store: 16 lanes = one contiguous 256 B row segment.
        #pragma unroll
        for (int it2 = 0; it2 < 4; ++it2) {
            const int id = it2 * 256 + tid;
            const int rr = id >> 4, off = (id & 15) * 8;
            *(uint4*)(W + ((size_t)b * NN + J + s * 64 + rr) * NN + I + off) =
                *(const uint4*)&WtT[rr * 136 + off];
        }
        LGKM_BAR();   // pass reads done before next pass / phase overwrites
    }

    // Denom butterflies + atomics WHILE the W(J,I) store stream drains.
    #pragma unroll
    for (int i = 0; i < 4; ++i) {
        #pragma unroll
        for (int r = 0; r < 4; ++r) {
            float s = rowpart[i][r];
            s += __shfl_xor(s, 1);
            s += __shfl_xor(s, 2);
            s += __shfl_xor(s, 4);
            s += __shfl_xor(s, 8);
            if (m_ == 0)
                atomicAdd(&denom[b * NN + I + wr * 64 + i * 16 + quad * 4 + r], s);
        }
    }
    if (!diag) {
        #pragma unroll
        for (int j = 0; j < 4; ++j) {
            float s = colpart[j];
            s += __shfl_xor(s, 16);
            s += __shfl_xor(s, 32);
            if (quad == 0)
                atomicAdd(&denom[b * NN + J + wc * 64 + j * 16 + m_], s);
        }
    }

    // ---- Phase 2 (off-diag): W(I,J) row-major, two 64-row passes ----
    if (!diag) {
        _Float16* Wt = smem;   // 64 rows x 136 col-pitch = 17408 B
        #pragma unroll
        for (int s = 0; s < 2; ++s) {
            if (wr == s) {    // waves owning srows [s*64, s*64+64)
                #pragma unroll
                for (int i = 0; i < 4; ++i) {
                    const int lr = i * 16 + quad * 4;  // srow - s*64
                    #pragma unroll
                    for (int j = 0; j < 4; ++j) {
                        const int col = wc * 64 + j * 16 + m_;
                        #pragma unroll
                        for (int r = 0; r < 4; ++r)
                            Wt[(lr + r) * 136 + col] = wq[i][j][r];
                    }
                }
            }
            LGKM_BAR();
            #pragma unroll
            for (int it2 = 0; it2 < 4; ++it2) {
                const int id = it2 * 256 + tid;
                const int rr = id >> 4, off = (id & 15) * 8;
                *(uint4*)(W + ((size_t)b * NN + I + s * 64 + rr) * NN + J + off) =
                    *(const uint4*)&Wt[rr * 136 + off];
            }
            LGKM_BAR();
        }
    }
}

// ---------------------------------------------------------------------------
// K3 (R14 structure + denom-load hoist): O = (W @ V) * (1/denom_i).
// 128x128 tile, 4-wave blocks, single-buffer 32.5 KiB LDS -> 4 blocks/CU,
// grid 1024 = 4 full rounds. W staging cached (L3-resident); out stores NT;
// XCD batch-pinned, 4 D-blocks of a W row-panel on adjacent same-XCD slots.
// NEW: denom global load issued BEFORE the K-loop (latency hidden under
// the whole GEMM; held in a register until the epilogue).
// ---------------------------------------------------------------------------
__global__ __launch_bounds__(256, 4) void k_pv(const _Float16* __restrict__ W,
                                               const _Float16* __restrict__ vT,
                                               const float* __restrict__ denom,
                                               float* __restrict__ out) {
    __shared__ _Float16 As[8192];      // [128][64]
    __shared__ _Float16 Bs[8192];      // [128][64]
    __shared__ float rdI[128];
    const int tid = threadIdx.x;
    const int lane = tid & 63, w = tid >> 6;  // 4 waves
    const int wr = w >> 1, wc = w & 1;        // 2 x 2 wave grid
    const int m_ = lane & 15, quad = lane >> 4;

    // XCD pinning: 1024 blocks, 128 slots/XCD, 2 batches/XCD.
    const int bx = blockIdx.x;
    const int xcd = bx & 7, slot = bx >> 3;        // slot 0..127
    const int b  = (slot >> 6) * 8 + xcd;          // 2 batches/XCD
    const int r_ = slot & 63;                      // 64 blocks/batch
    const int I  = (r_ >> 2) * 128;                // 16 I-tiles
    const int D0 = (r_ & 3) * 128;                 // 4 D-blocks adjacent

    // Hoisted denom load: latency hides under the entire K-loop.
    float dv = 0.f;
    if (tid < 128) dv = denom[b * NN + I + tid];

    const _Float16* Ab = W  + ((size_t)b * NN + I) * NN;
    const _Float16* Bb = vT + ((size_t)b * DD + D0) * NN;

    const int sub = lane >> 3;
    const int swc = (lane & 7) ^ sub;
    // A: 128 rows, wave stages 32 rows (4 chunks of 8). B: same.
    const _Float16* agl = Ab + (size_t)(w * 32 + sub) * NN + swc * 8;
    const _Float16* bgl = Bb + (size_t)(w * 32 + sub) * NN + swc * 8;

    f32x4 acc[4][4];
    #pragma unroll
    for (int i = 0; i < 4; ++i)
        #pragma unroll
        for (int j = 0; j < 4; ++j) acc[i][j] = (f32x4){0.f, 0.f, 0.f, 0.f};

    for (int kb = 0; kb < NN / 64; ++kb) {
        const int k0 = kb * 64;
        #pragma unroll
        for (int c = 0; c < 4; ++c) {
            async_ld16(&As[(w * 32 + c * 8) * 64], agl + (size_t)c * 8 * NN + k0);
            async_ld16(&Bs[(w * 32 + c * 8) * 64], bgl + (size_t)c * 8 * NN + k0);
        }
        VM_WAIT(0);
        RAW_BAR();
        __builtin_amdgcn_s_setprio(1);
        #pragma unroll
        for (int kc = 0; kc < 2; ++kc) {
            f16x8 af[4], bf[4];
            #pragma unroll
            for (int t = 0; t < 4; ++t) {
                const int Ra = wr * 64 + t * 16 + m_;
                const int Rb = wc * 64 + t * 16 + m_;
                af[t] = *(const f16x8*)&As[Ra * 64 + (((kc * 4 + quad) ^ (Ra & 7)) * 8)];
                bf[t] = *(const f16x8*)&Bs[Rb * 64 + (((kc * 4 + quad) ^ (Rb & 7)) * 8)];
            }
            #pragma unroll
            for (int i = 0; i < 4; ++i)
                #pragma unroll
                for (int j = 0; j < 4; ++j)
                    acc[i][j] = __builtin_amdgcn_mfma_f32_16x16x32_f16(af[i], bf[j], acc[i][j], 0, 0, 0);
        }
        __builtin_amdgcn_s_setprio(0);
        RAW_BAR();   // all waves done reading before next stage overwrites
    }

    // Epilogue: broadcast reciprocals via LDS, NT stores.
    if (tid < 128) rdI[tid] = 1.0f / dv;
    LGKM_BAR();

    #pragma unroll
    for (int i = 0; i < 4; ++i) {
        const int rowb = wr * 64 + i * 16 + quad * 4;
        #pragma unroll
        for (int r = 0; r < 4; ++r) {
            const float sc = rdI[rowb + r];
            float* op = out + ((size_t)(b * NN + I + rowb + r)) * DD + D0;
            #pragma unroll
            for (int j = 0; j < 4; ++j)
                __builtin_nontemporal_store(acc[i][j][r] * sc,
                                            op + wc * 64 + j * 16 + m_);
        }
    }
}

// ---------------------------------------------------------------------------
extern "C" void kernel_launch(void* const* d_in, const int* in_sizes, int n_in,
                              void* d_out, int out_size, void* d_ws, size_t ws_size,
                              hipStream_t stream) {
    const float* x = (const float*)d_in[0];
    char* ws = (char*)d_ws;
    _Float16* xhn   = (_Float16*)(ws);                        // 32 MiB normalized fp16
    _Float16* vT    = (_Float16*)(ws + (size_t)33554432);     // 32 MiB fp16 x^T
    _Float16* W     = (_Float16*)(ws + (size_t)67108864);     // 128 MiB fp16 exp-scores
    float*    denom = (float*)   (ws + (size_t)201326592);    // 128 KiB
    float*    out   = (float*)d_out;

    k_prep<<<dim3(NN / 64, BB), 256, 0, stream>>>(x, xhn, vT, denom);
    const int npairs = (NN / 128) * (NN / 128 + 1) / 2;   // 136
    k_scores<<<dim3(npairs, 1, BB), 256, 0, stream>>>(xhn, W, denom);
    // 1024 blocks = 4 blocks/CU (32.5 KiB LDS, 4-wave blocks), XCD batch-pinned
    k_pv<<<dim3(1024, 1, 1), 256, 0, stream>>>(W, vT, denom, out);
}

// Round 16
// 170.660 us; speedup vs baseline: 1.9729x; 1.9729x over previous
//
#include <hip/hip_runtime.h>
#include <hip/hip_bf16.h>
#include <cstdint>
#include <cstddef>

// Problem shape (fixed): x [B=16][N=2048][D=512] fp32
#define BB 16
#define NN 2048
#define DD 512

typedef _Float16 f16x8 __attribute__((ext_vector_type(8)));
typedef _Float16 f16x4 __attribute__((ext_vector_type(4)));
typedef float f32x4 __attribute__((ext_vector_type(4)));
typedef unsigned int u32x4 __attribute__((ext_vector_type(4)));

// Async global->LDS, 16 B per lane. LDS dest = wave-uniform base + lane*16.
__device__ __forceinline__ void async_ld16(void* lds, const void* g) {
    __builtin_amdgcn_global_load_lds(
        (const __attribute__((address_space(1))) unsigned int*)(uintptr_t)g,
        (__attribute__((address_space(3))) unsigned int*)(uint32_t)(uintptr_t)lds,
        16, 0, 0);
}

#define VM_WAIT(n) asm volatile("s_waitcnt vmcnt(" #n ")" ::: "memory")
#define RAW_BAR()  do { asm volatile("" ::: "memory"); __builtin_amdgcn_s_barrier(); asm volatile("" ::: "memory"); } while (0)
// LDS-order-only barrier: global stores/atomics keep draining.
#define LGKM_BAR() do { asm volatile("s_waitcnt lgkmcnt(0)" ::: "memory"); \
                        __builtin_amdgcn_s_barrier();                      \
                        __builtin_amdgcn_sched_barrier(0); } while (0)

// ---------------------------------------------------------------------------
// K1 (fused): read x ONCE (non-temporal: stream-once). Per 64-row slab:
// norms, xhn (normalized fp16), vT (fp16 transpose), denom zero-init.
// grid (NN/64, BB), 256 threads.
// ---------------------------------------------------------------------------
__global__ __launch_bounds__(256) void k_prep(const float* __restrict__ x,
                                              _Float16* __restrict__ xhn,
                                              _Float16* __restrict__ vT,
                                              float* __restrict__ denom) {
    __shared__ _Float16 t[512 * 66];     // [d][j], pitch 66 halves
    const int tid = threadIdx.x, lane = tid & 63, w = tid >> 6;
    const int b = blockIdx.y, j0 = blockIdx.x * 64;
    if (tid < 64) denom[b * NN + j0 + tid] = 0.f;
    const float* xb = x + ((size_t)b * NN + j0) * DD;

    for (int rr = 0; rr < 16; ++rr) {
        const int jj = w * 16 + rr;                 // row within slab
        const float* xr = xb + (size_t)jj * DD;
        f32x4 a = __builtin_nontemporal_load((const f32x4*)xr + lane);
        f32x4 c = __builtin_nontemporal_load((const f32x4*)xr + lane + 64);
        float ss = a[0]*a[0] + a[1]*a[1] + a[2]*a[2] + a[3]*a[3]
                 + c[0]*c[0] + c[1]*c[1] + c[2]*c[2] + c[3]*c[3];
        #pragma unroll
        for (int o = 1; o < 64; o <<= 1) ss += __shfl_xor(ss, o);
        const float rn = 1.0f / sqrtf(ss);
        // normalized fp16 row (coalesced 8B stores)
        _Float16* dst = xhn + ((size_t)b * NN + j0 + jj) * DD;
        f16x4 v0 = {(_Float16)(a[0]*rn), (_Float16)(a[1]*rn), (_Float16)(a[2]*rn), (_Float16)(a[3]*rn)};
        f16x4 v1 = {(_Float16)(c[0]*rn), (_Float16)(c[1]*rn), (_Float16)(c[2]*rn), (_Float16)(c[3]*rn)};
        *(f16x4*)(dst + 4 * lane) = v0;
        *(f16x4*)(dst + 256 + 4 * lane) = v1;
        // unnormalized fp16 into transposed LDS tile
        const int d0 = 4 * lane, d1 = 256 + 4 * lane;
        t[(d0 + 0) * 66 + jj] = (_Float16)a[0];
        t[(d0 + 1) * 66 + jj] = (_Float16)a[1];
        t[(d0 + 2) * 66 + jj] = (_Float16)a[2];
        t[(d0 + 3) * 66 + jj] = (_Float16)a[3];
        t[(d1 + 0) * 66 + jj] = (_Float16)c[0];
        t[(d1 + 1) * 66 + jj] = (_Float16)c[1];
        t[(d1 + 2) * 66 + jj] = (_Float16)c[2];
        t[(d1 + 3) * 66 + jj] = (_Float16)c[3];
    }
    LGKM_BAR();   // xhn global stores keep draining under the vT phase
    // store vT rows: 512 d x 8 chunks of 8 halves; 4B-aligned b32 LDS reads.
    #pragma unroll
    for (int it = 0; it < 16; ++it) {
        const int id = it * 256 + tid;
        const int d = id >> 3, ch = (id & 7) * 8;
        const uint32_t* tp = (const uint32_t*)&t[d * 66 + ch];
        uint4 v = {tp[0], tp[1], tp[2], tp[3]};
        *(uint4*)(vT + ((size_t)b * DD + d) * NN + j0 + ch) = v;
    }
}

// ---------------------------------------------------------------------------
// K2 (REVERTED to R14 exact — R15's launch_bounds(256,5) forced VGPR 64->48,
// spilling the 64-reg accumulator to scratch: WRITE_SIZE 141->520 MB, 3x
// slower. Guideline-6 floor: acc+wq+frags need ~90 VGPRs -> 4 blocks/CU max).
// W = exp( xhn xhn^T ), symmetric-triangular. 128x128 block, 4 waves,
// single-buffered BK=64, 34 KiB LDS -> 4 blocks/CU, XCD tile-pair swizzle,
// lane-coalesced 256B-segment stores, stores-before-atomics ordering.
// ---------------------------------------------------------------------------
__global__ __launch_bounds__(256, 4) void k_scores(const _Float16* __restrict__ xhn,
                                                   _Float16* __restrict__ W,
                                                   float* __restrict__ denom) {
    __shared__ _Float16 smem[17408];          // As[8192]+Bs[8192]; epi: 128x136
    const int tid = threadIdx.x;
    const int lane = tid & 63, wv = tid >> 6;
    const int wr = wv >> 1, wc = wv & 1;
    const int m_ = lane & 15, quad = lane >> 4;
    const int b = blockIdx.z;

    // XCD swizzle: 136 = 8 * 17 -> each XCD gets 17 consecutive pairs.
    const int swz = (blockIdx.x % 8) * 17 + blockIdx.x / 8;
    int rem = swz, ti = 0, rowlen = NN / 128;
    while (rem >= rowlen) { rem -= rowlen; ++ti; --rowlen; }
    const int tj = ti + rem;
    const int I = ti * 128, J = tj * 128;
    const bool diag = (ti == tj);

    const _Float16* Ab = xhn + ((size_t)b * NN + I) * DD;
    const _Float16* Bb = xhn + ((size_t)b * NN + J) * DD;

    f32x4 acc[4][4];
    #pragma unroll
    for (int i = 0; i < 4; ++i)
        #pragma unroll
        for (int j = 0; j < 4; ++j) acc[i][j] = (f32x4){0.f, 0.f, 0.f, 0.f};

    const int sub = lane >> 3;
    const int swc = (lane & 7) ^ sub;
    const _Float16* agl = Ab + (size_t)(wv * 32 + sub) * DD + swc * 8;
    const _Float16* bgl = Bb + (size_t)(wv * 32 + sub) * DD + swc * 8;
    _Float16* As = smem;
    _Float16* Bs = smem + 8192;

    for (int kb = 0; kb < DD / 64; ++kb) {
        const int k0 = kb * 64;
        #pragma unroll
        for (int c = 0; c < 4; ++c) {
            async_ld16(&As[(wv * 32 + c * 8) * 64], agl + (size_t)c * 8 * DD + k0);
            async_ld16(&Bs[(wv * 32 + c * 8) * 64], bgl + (size_t)c * 8 * DD + k0);
        }
        VM_WAIT(0);
        RAW_BAR();
        __builtin_amdgcn_s_setprio(1);
        #pragma unroll
        for (int kc = 0; kc < 2; ++kc) {
            f16x8 af[4], bf[4];
            #pragma unroll
            for (int t = 0; t < 4; ++t) {
                const int Ra = wr * 64 + t * 16 + m_;
                const int Rb = wc * 64 + t * 16 + m_;
                af[t] = *(const f16x8*)&As[Ra * 64 + (((kc * 4 + quad) ^ (Ra & 7)) * 8)];
                bf[t] = *(const f16x8*)&Bs[Rb * 64 + (((kc * 4 + quad) ^ (Rb & 7)) * 8)];
            }
            #pragma unroll
            for (int i = 0; i < 4; ++i)
                #pragma unroll
                for (int j = 0; j < 4; ++j)
                    acc[i][j] = __builtin_amdgcn_mfma_f32_16x16x32_f16(af[i], bf[j], acc[i][j], 0, 0, 0);
        }
        __builtin_amdgcn_s_setprio(0);
        RAW_BAR();   // all waves done reading before next stage overwrites
    }

    // Epilogue: exp into packed f16x4; register row/col partial sums.
    f16x4 wq[4][4];
    float rowpart[4][4];
    float colpart[4] = {0.f, 0.f, 0.f, 0.f};
    #pragma unroll
    for (int i = 0; i < 4; ++i)
        #pragma unroll
        for (int r = 0; r < 4; ++r) rowpart[i][r] = 0.f;

    #pragma unroll
    for (int i = 0; i < 4; ++i) {
        #pragma unroll
        for (int j = 0; j < 4; ++j) {
            #pragma unroll
            for (int r = 0; r < 4; ++r) {
                const float w = __expf(acc[i][j][r]);
                wq[i][j][r] = (_Float16)w;
                rowpart[i][r] += w;
                colpart[j] += w;
            }
        }
    }

    // Phase 1 FIRST: WtT[col][row] (stride 136) -> coalesced W(J,I) stores.
    _Float16* WtT = smem;
    #pragma unroll
    for (int i = 0; i < 4; ++i) {
        const int rowb = wr * 64 + i * 16 + quad * 4;
        #pragma unroll
        for (int j = 0; j < 4; ++j) {
            const int col = wc * 64 + j * 16 + m_;
            *(f16x4*)&WtT[col * 136 + rowb] = wq[i][j];
        }
    }
    LGKM_BAR();
    // lane-coalesced store: 16 lanes = one contiguous 256 B row segment.
    #pragma unroll
    for (int it2 = 0; it2 < 8; ++it2) {
        const int id = it2 * 256 + tid;
        const int rr = id >> 4, off = (id & 15) * 8;
        *(uint4*)(W + ((size_t)b * NN + J + rr) * NN + I + off) =
            *(const uint4*)&WtT[rr * 136 + off];
    }

    // Denom butterflies + atomics WHILE the W(J,I) store stream drains.
    #pragma unroll
    for (int i = 0; i < 4; ++i) {
        #pragma unroll
        for (int r = 0; r < 4; ++r) {
            float s = rowpart[i][r];
            s += __shfl_xor(s, 1);
            s += __shfl_xor(s, 2);
            s += __shfl_xor(s, 4);
            s += __shfl_xor(s, 8);
            if (m_ == 0)
                atomicAdd(&denom[b * NN + I + wr * 64 + i * 16 + quad * 4 + r], s);
        }
    }
    if (!diag) {
        #pragma unroll
        for (int j = 0; j < 4; ++j) {
            float s = colpart[j];
            s += __shfl_xor(s, 16);
            s += __shfl_xor(s, 32);
            if (quad == 0)
                atomicAdd(&denom[b * NN + J + wc * 64 + j * 16 + m_], s);
        }
    }

    // Phase 2 (off-diag): row-major Wt -> coalesced W(I,J).
    if (!diag) {
        LGKM_BAR();   // phase-1 LDS reads done; stores/atomics still in flight
        _Float16* Wt = smem;
        #pragma unroll
        for (int i = 0; i < 4; ++i) {
            const int rowb = wr * 64 + i * 16 + quad * 4;
            #pragma unroll
            for (int j = 0; j < 4; ++j) {
                const int col = wc * 64 + j * 16 + m_;
                #pragma unroll
                for (int r = 0; r < 4; ++r)
                    Wt[(rowb + r) * 136 + col] = wq[i][j][r];
            }
        }
        LGKM_BAR();
        #pragma unroll
        for (int it2 = 0; it2 < 8; ++it2) {
            const int id = it2 * 256 + tid;
            const int rr = id >> 4, off = (id & 15) * 8;
            *(uint4*)(W + ((size_t)b * NN + I + rr) * NN + J + off) =
                *(const uint4*)&Wt[rr * 136 + off];
        }
    }
}

// ---------------------------------------------------------------------------
// K3 (R14 structure + denom-load hoist, kept from R15): O = (W@V)*(1/denom).
// 128x128 tile, 4-wave blocks, single-buffer 32.5 KiB LDS -> 4 blocks/CU,
// grid 1024 = 4 full rounds. W staging cached (L3-resident); out stores NT;
// XCD batch-pinned, 4 D-blocks of a W row-panel on adjacent same-XCD slots.
// ---------------------------------------------------------------------------
__global__ __launch_bounds__(256, 4) void k_pv(const _Float16* __restrict__ W,
                                               const _Float16* __restrict__ vT,
                                               const float* __restrict__ denom,
                                               float* __restrict__ out) {
    __shared__ _Float16 As[8192];      // [128][64]
    __shared__ _Float16 Bs[8192];      // [128][64]
    __shared__ float rdI[128];
    const int tid = threadIdx.x;
    const int lane = tid & 63, w = tid >> 6;  // 4 waves
    const int wr = w >> 1, wc = w & 1;        // 2 x 2 wave grid
    const int m_ = lane & 15, quad = lane >> 4;

    // XCD pinning: 1024 blocks, 128 slots/XCD, 2 batches/XCD.
    const int bx = blockIdx.x;
    const int xcd = bx & 7, slot = bx >> 3;        // slot 0..127
    const int b  = (slot >> 6) * 8 + xcd;          // 2 batches/XCD
    const int r_ = slot & 63;                      // 64 blocks/batch
    const int I  = (r_ >> 2) * 128;                // 16 I-tiles
    const int D0 = (r_ & 3) * 128;                 // 4 D-blocks adjacent

    // Hoisted denom load: latency hides under the entire K-loop.
    float dv = 0.f;
    if (tid < 128) dv = denom[b * NN + I + tid];

    const _Float16* Ab = W  + ((size_t)b * NN + I) * NN;
    const _Float16* Bb = vT + ((size_t)b * DD + D0) * NN;

    const int sub = lane >> 3;
    const int swc = (lane & 7) ^ sub;
    // A: 128 rows, wave stages 32 rows (4 chunks of 8). B: same.
    const _Float16* agl = Ab + (size_t)(w * 32 + sub) * NN + swc * 8;
    const _Float16* bgl = Bb + (size_t)(w * 32 + sub) * NN + swc * 8;

    f32x4 acc[4][4];
    #pragma unroll
    for (int i = 0; i < 4; ++i)
        #pragma unroll
        for (int j = 0; j < 4; ++j) acc[i][j] = (f32x4){0.f, 0.f, 0.f, 0.f};

    for (int kb = 0; kb < NN / 64; ++kb) {
        const int k0 = kb * 64;
        #pragma unroll
        for (int c = 0; c < 4; ++c) {
            async_ld16(&As[(w * 32 + c * 8) * 64], agl + (size_t)c * 8 * NN + k0);
            async_ld16(&Bs[(w * 32 + c * 8) * 64], bgl + (size_t)c * 8 * NN + k0);
        }
        VM_WAIT(0);
        RAW_BAR();
        __builtin_amdgcn_s_setprio(1);
        #pragma unroll
        for (int kc = 0; kc < 2; ++kc) {
            f16x8 af[4], bf[4];
            #pragma unroll
            for (int t = 0; t < 4; ++t) {
                const int Ra = wr * 64 + t * 16 + m_;
                const int Rb = wc * 64 + t * 16 + m_;
                af[t] = *(const f16x8*)&As[Ra * 64 + (((kc * 4 + quad) ^ (Ra & 7)) * 8)];
                bf[t] = *(const f16x8*)&Bs[Rb * 64 + (((kc * 4 + quad) ^ (Rb & 7)) * 8)];
            }
            #pragma unroll
            for (int i = 0; i < 4; ++i)
                #pragma unroll
                for (int j = 0; j < 4; ++j)
                    acc[i][j] = __builtin_amdgcn_mfma_f32_16x16x32_f16(af[i], bf[j], acc[i][j], 0, 0, 0);
        }
        __builtin_amdgcn_s_setprio(0);
        RAW_BAR();   // all waves done reading before next stage overwrites
    }

    // Epilogue: broadcast reciprocals via LDS, NT stores.
    if (tid < 128) rdI[tid] = 1.0f / dv;
    LGKM_BAR();

    #pragma unroll
    for (int i = 0; i < 4; ++i) {
        const int rowb = wr * 64 + i * 16 + quad * 4;
        #pragma unroll
        for (int r = 0; r < 4; ++r) {
            const float sc = rdI[rowb + r];
            float* op = out + ((size_t)(b * NN + I + rowb + r)) * DD + D0;
            #pragma unroll
            for (int j = 0; j < 4; ++j)
                __builtin_nontemporal_store(acc[i][j][r] * sc,
                                            op + wc * 64 + j * 16 + m_);
        }
    }
}

// ---------------------------------------------------------------------------
extern "C" void kernel_launch(void* const* d_in, const int* in_sizes, int n_in,
                              void* d_out, int out_size, void* d_ws, size_t ws_size,
                              hipStream_t stream) {
    const float* x = (const float*)d_in[0];
    char* ws = (char*)d_ws;
    _Float16* xhn   = (_Float16*)(ws);                        // 32 MiB normalized fp16
    _Float16* vT    = (_Float16*)(ws + (size_t)33554432);     // 32 MiB fp16 x^T
    _Float16* W     = (_Float16*)(ws + (size_t)67108864);     // 128 MiB fp16 exp-scores
    float*    denom = (float*)   (ws + (size_t)201326592);    // 128 KiB
    float*    out   = (float*)d_out;

    k_prep<<<dim3(NN / 64, BB), 256, 0, stream>>>(x, xhn, vT, denom);
    const int npairs = (NN / 128) * (NN / 128 + 1) / 2;   // 136
    k_scores<<<dim3(npairs, 1, BB), 256, 0, stream>>>(xhn, W, denom);
    // 1024 blocks = 4 blocks/CU (32.5 KiB LDS, 4-wave blocks), XCD batch-pinned
    k_pv<<<dim3(1024, 1, 1), 256, 0, stream>>>(W, vT, denom, out);
}

// Round 19
// 170.539 us; speedup vs baseline: 1.9743x; 1.0007x over previous
//
#include <hip/hip_runtime.h>
#include <hip/hip_bf16.h>
#include <cstdint>
#include <cstddef>

// Problem shape (fixed): x [B=16][N=2048][D=512] fp32
#define BB 16
#define NN 2048
#define DD 512

typedef _Float16 f16x8 __attribute__((ext_vector_type(8)));
typedef _Float16 f16x4 __attribute__((ext_vector_type(4)));
typedef float f32x4 __attribute__((ext_vector_type(4)));
typedef unsigned int u32x4 __attribute__((ext_vector_type(4)));

// Async global->LDS, 16 B per lane. LDS dest = wave-uniform base + lane*16.
__device__ __forceinline__ void async_ld16(void* lds, const void* g) {
    __builtin_amdgcn_global_load_lds(
        (const __attribute__((address_space(1))) unsigned int*)(uintptr_t)g,
        (__attribute__((address_space(3))) unsigned int*)(uint32_t)(uintptr_t)lds,
        16, 0, 0);
}

#define VM_WAIT(n) asm volatile("s_waitcnt vmcnt(" #n ")" ::: "memory")
#define RAW_BAR()  do { asm volatile("" ::: "memory"); __builtin_amdgcn_s_barrier(); asm volatile("" ::: "memory"); } while (0)
// LDS-order-only barrier: global stores/atomics keep draining.
#define LGKM_BAR() do { asm volatile("s_waitcnt lgkmcnt(0)" ::: "memory"); \
                        __builtin_amdgcn_s_barrier();                      \
                        __builtin_amdgcn_sched_barrier(0); } while (0)

// ---------------------------------------------------------------------------
// K1 (fused): read x ONCE (non-temporal: stream-once). Per 64-row slab:
// norms, xhn (normalized fp16), vT (fp16 transpose), denom zero-init.
// grid (NN/64, BB), 256 threads.
// ---------------------------------------------------------------------------
__global__ __launch_bounds__(256) void k_prep(const float* __restrict__ x,
                                              _Float16* __restrict__ xhn,
                                              _Float16* __restrict__ vT,
                                              float* __restrict__ denom) {
    __shared__ _Float16 t[512 * 66];     // [d][j], pitch 66 halves
    const int tid = threadIdx.x, lane = tid & 63, w = tid >> 6;
    const int b = blockIdx.y, j0 = blockIdx.x * 64;
    if (tid < 64) denom[b * NN + j0 + tid] = 0.f;
    const float* xb = x + ((size_t)b * NN + j0) * DD;

    for (int rr = 0; rr < 16; ++rr) {
        const int jj = w * 16 + rr;                 // row within slab
        const float* xr = xb + (size_t)jj * DD;
        f32x4 a = __builtin_nontemporal_load((const f32x4*)xr + lane);
        f32x4 c = __builtin_nontemporal_load((const f32x4*)xr + lane + 64);
        float ss = a[0]*a[0] + a[1]*a[1] + a[2]*a[2] + a[3]*a[3]
                 + c[0]*c[0] + c[1]*c[1] + c[2]*c[2] + c[3]*c[3];
        #pragma unroll
        for (int o = 1; o < 64; o <<= 1) ss += __shfl_xor(ss, o);
        const float rn = 1.0f / sqrtf(ss);
        // normalized fp16 row (coalesced 8B stores)
        _Float16* dst = xhn + ((size_t)b * NN + j0 + jj) * DD;
        f16x4 v0 = {(_Float16)(a[0]*rn), (_Float16)(a[1]*rn), (_Float16)(a[2]*rn), (_Float16)(a[3]*rn)};
        f16x4 v1 = {(_Float16)(c[0]*rn), (_Float16)(c[1]*rn), (_Float16)(c[2]*rn), (_Float16)(c[3]*rn)};
        *(f16x4*)(dst + 4 * lane) = v0;
        *(f16x4*)(dst + 256 + 4 * lane) = v1;
        // unnormalized fp16 into transposed LDS tile
        const int d0 = 4 * lane, d1 = 256 + 4 * lane;
        t[(d0 + 0) * 66 + jj] = (_Float16)a[0];
        t[(d0 + 1) * 66 + jj] = (_Float16)a[1];
        t[(d0 + 2) * 66 + jj] = (_Float16)a[2];
        t[(d0 + 3) * 66 + jj] = (_Float16)a[3];
        t[(d1 + 0) * 66 + jj] = (_Float16)c[0];
        t[(d1 + 1) * 66 + jj] = (_Float16)c[1];
        t[(d1 + 2) * 66 + jj] = (_Float16)c[2];
        t[(d1 + 3) * 66 + jj] = (_Float16)c[3];
    }
    LGKM_BAR();   // xhn global stores keep draining under the vT phase
    // store vT rows: 512 d x 8 chunks of 8 halves; 4B-aligned b32 LDS reads.
    #pragma unroll
    for (int it = 0; it < 16; ++it) {
        const int id = it * 256 + tid;
        const int d = id >> 3, ch = (id & 7) * 8;
        const uint32_t* tp = (const uint32_t*)&t[d * 66 + ch];
        uint4 v = {tp[0], tp[1], tp[2], tp[3]};
        *(uint4*)(vT + ((size_t)b * DD + d) * NN + j0 + ch) = v;
    }
}

// ---------------------------------------------------------------------------
// K2 (R14/R16 final): W = exp( xhn xhn^T ), symmetric-triangular.
// 128x128 block, 4 waves, single-buffered BK=64, 34 KiB LDS -> 4 blocks/CU
// (VGPR-capped max: acc+wq+frags ~90 VGPRs; 5 blocks/CU spills — R15),
// XCD tile-pair swizzle, lane-coalesced 256B-segment stores,
// stores-before-atomics ordering, LGKM-only barriers.
// ---------------------------------------------------------------------------
__global__ __launch_bounds__(256, 4) void k_scores(const _Float16* __restrict__ xhn,
                                                   _Float16* __restrict__ W,
                                                   float* __restrict__ denom) {
    __shared__ _Float16 smem[17408];          // As[8192]+Bs[8192]; epi: 128x136
    const int tid = threadIdx.x;
    const int lane = tid & 63, wv = tid >> 6;
    const int wr = wv >> 1, wc = wv & 1;
    const int m_ = lane & 15, quad = lane >> 4;
    const int b = blockIdx.z;

    // XCD swizzle: 136 = 8 * 17 -> each XCD gets 17 consecutive pairs.
    const int swz = (blockIdx.x % 8) * 17 + blockIdx.x / 8;
    int rem = swz, ti = 0, rowlen = NN / 128;
    while (rem >= rowlen) { rem -= rowlen; ++ti; --rowlen; }
    const int tj = ti + rem;
    const int I = ti * 128, J = tj * 128;
    const bool diag = (ti == tj);

    const _Float16* Ab = xhn + ((size_t)b * NN + I) * DD;
    const _Float16* Bb = xhn + ((size_t)b * NN + J) * DD;

    f32x4 acc[4][4];
    #pragma unroll
    for (int i = 0; i < 4; ++i)
        #pragma unroll
        for (int j = 0; j < 4; ++j) acc[i][j] = (f32x4){0.f, 0.f, 0.f, 0.f};

    const int sub = lane >> 3;
    const int swc = (lane & 7) ^ sub;
    const _Float16* agl = Ab + (size_t)(wv * 32 + sub) * DD + swc * 8;
    const _Float16* bgl = Bb + (size_t)(wv * 32 + sub) * DD + swc * 8;
    _Float16* As = smem;
    _Float16* Bs = smem + 8192;

    for (int kb = 0; kb < DD / 64; ++kb) {
        const int k0 = kb * 64;
        #pragma unroll
        for (int c = 0; c < 4; ++c) {
            async_ld16(&As[(wv * 32 + c * 8) * 64], agl + (size_t)c * 8 * DD + k0);
            async_ld16(&Bs[(wv * 32 + c * 8) * 64], bgl + (size_t)c * 8 * DD + k0);
        }
        VM_WAIT(0);
        RAW_BAR();
        __builtin_amdgcn_s_setprio(1);
        #pragma unroll
        for (int kc = 0; kc < 2; ++kc) {
            f16x8 af[4], bf[4];
            #pragma unroll
            for (int t = 0; t < 4; ++t) {
                const int Ra = wr * 64 + t * 16 + m_;
                const int Rb = wc * 64 + t * 16 + m_;
                af[t] = *(const f16x8*)&As[Ra * 64 + (((kc * 4 + quad) ^ (Ra & 7)) * 8)];
                bf[t] = *(const f16x8*)&Bs[Rb * 64 + (((kc * 4 + quad) ^ (Rb & 7)) * 8)];
            }
            #pragma unroll
            for (int i = 0; i < 4; ++i)
                #pragma unroll
                for (int j = 0; j < 4; ++j)
                    acc[i][j] = __builtin_amdgcn_mfma_f32_16x16x32_f16(af[i], bf[j], acc[i][j], 0, 0, 0);
        }
        __builtin_amdgcn_s_setprio(0);
        RAW_BAR();   // all waves done reading before next stage overwrites
    }

    // Epilogue: exp into packed f16x4; register row/col partial sums.
    f16x4 wq[4][4];
    float rowpart[4][4];
    float colpart[4] = {0.f, 0.f, 0.f, 0.f};
    #pragma unroll
    for (int i = 0; i < 4; ++i)
        #pragma unroll
        for (int r = 0; r < 4; ++r) rowpart[i][r] = 0.f;

    #pragma unroll
    for (int i = 0; i < 4; ++i) {
        #pragma unroll
        for (int j = 0; j < 4; ++j) {
            #pragma unroll
            for (int r = 0; r < 4; ++r) {
                const float w = __expf(acc[i][j][r]);
                wq[i][j][r] = (_Float16)w;
                rowpart[i][r] += w;
                colpart[j] += w;
            }
        }
    }

    // Phase 1 FIRST: WtT[col][row] (stride 136) -> coalesced W(J,I) stores.
    _Float16* WtT = smem;
    #pragma unroll
    for (int i = 0; i < 4; ++i) {
        const int rowb = wr * 64 + i * 16 + quad * 4;
        #pragma unroll
        for (int j = 0; j < 4; ++j) {
            const int col = wc * 64 + j * 16 + m_;
            *(f16x4*)&WtT[col * 136 + rowb] = wq[i][j];
        }
    }
    LGKM_BAR();
    // lane-coalesced store: 16 lanes = one contiguous 256 B row segment.
    #pragma unroll
    for (int it2 = 0; it2 < 8; ++it2) {
        const int id = it2 * 256 + tid;
        const int rr = id >> 4, off = (id & 15) * 8;
        *(uint4*)(W + ((size_t)b * NN + J + rr) * NN + I + off) =
            *(const uint4*)&WtT[rr * 136 + off];
    }

    // Denom butterflies + atomics WHILE the W(J,I) store stream drains.
    #pragma unroll
    for (int i = 0; i < 4; ++i) {
        #pragma unroll
        for (int r = 0; r < 4; ++r) {
            float s = rowpart[i][r];
            s += __shfl_xor(s, 1);
            s += __shfl_xor(s, 2);
            s += __shfl_xor(s, 4);
            s += __shfl_xor(s, 8);
            if (m_ == 0)
                atomicAdd(&denom[b * NN + I + wr * 64 + i * 16 + quad * 4 + r], s);
        }
    }
    if (!diag) {
        #pragma unroll
        for (int j = 0; j < 4; ++j) {
            float s = colpart[j];
            s += __shfl_xor(s, 16);
            s += __shfl_xor(s, 32);
            if (quad == 0)
                atomicAdd(&denom[b * NN + J + wc * 64 + j * 16 + m_], s);
        }
    }

    // Phase 2 (off-diag): row-major Wt -> coalesced W(I,J).
    if (!diag) {
        LGKM_BAR();   // phase-1 LDS reads done; stores/atomics still in flight
        _Float16* Wt = smem;
        #pragma unroll
        for (int i = 0; i < 4; ++i) {
            const int rowb = wr * 64 + i * 16 + quad * 4;
            #pragma unroll
            for (int j = 0; j < 4; ++j) {
                const int col = wc * 64 + j * 16 + m_;
                #pragma unroll
                for (int r = 0; r < 4; ++r)
                    Wt[(rowb + r) * 136 + col] = wq[i][j][r];
            }
        }
        LGKM_BAR();
        #pragma unroll
        for (int it2 = 0; it2 < 8; ++it2) {
            const int id = it2 * 256 + tid;
            const int rr = id >> 4, off = (id & 15) * 8;
            *(uint4*)(W + ((size_t)b * NN + I + rr) * NN + J + off) =
                *(const uint4*)&Wt[rr * 136 + off];
        }
    }
}

// ---------------------------------------------------------------------------
// K3 (R14/R16 final): O = (W @ V) * (1/denom_i), fp32 out.
// 128x128 tile, 4-wave blocks, single-buffer 32.5 KiB LDS -> 4 blocks/CU,
// grid 1024 = 4 full rounds. W staging cached (L3-resident); out stores NT;
// XCD batch-pinned, 4 D-blocks of a W row-panel on adjacent same-XCD slots;
// denom load hoisted above the K-loop.
// ---------------------------------------------------------------------------
__global__ __launch_bounds__(256, 4) void k_pv(const _Float16* __restrict__ W,
                                               const _Float16* __restrict__ vT,
                                               const float* __restrict__ denom,
                                               float* __restrict__ out) {
    __shared__ _Float16 As[8192];      // [128][64]
    __shared__ _Float16 Bs[8192];      // [128][64]
    __shared__ float rdI[128];
    const int tid = threadIdx.x;
    const int lane = tid & 63, w = tid >> 6;  // 4 waves
    const int wr = w >> 1, wc = w & 1;        // 2 x 2 wave grid
    const int m_ = lane & 15, quad = lane >> 4;

    // XCD pinning: 1024 blocks, 128 slots/XCD, 2 batches/XCD.
    const int bx = blockIdx.x;
    const int xcd = bx & 7, slot = bx >> 3;        // slot 0..127
    const int b  = (slot >> 6) * 8 + xcd;          // 2 batches/XCD
    const int r_ = slot & 63;                      // 64 blocks/batch
    const int I  = (r_ >> 2) * 128;                // 16 I-tiles
    const int D0 = (r_ & 3) * 128;                 // 4 D-blocks adjacent

    // Hoisted denom load: latency hides under the entire K-loop.
    float dv = 0.f;
    if (tid < 128) dv = denom[b * NN + I + tid];

    const _Float16* Ab = W  + ((size_t)b * NN + I) * NN;
    const _Float16* Bb = vT + ((size_t)b * DD + D0) * NN;

    const int sub = lane >> 3;
    const int swc = (lane & 7) ^ sub;
    // A: 128 rows, wave stages 32 rows (4 chunks of 8). B: same.
    const _Float16* agl = Ab + (size_t)(w * 32 + sub) * NN + swc * 8;
    const _Float16* bgl = Bb + (size_t)(w * 32 + sub) * NN + swc * 8;

    f32x4 acc[4][4];
    #pragma unroll
    for (int i = 0; i < 4; ++i)
        #pragma unroll
        for (int j = 0; j < 4; ++j) acc[i][j] = (f32x4){0.f, 0.f, 0.f, 0.f};

    for (int kb = 0; kb < NN / 64; ++kb) {
        const int k0 = kb * 64;
        #pragma unroll
        for (int c = 0; c < 4; ++c) {
            async_ld16(&As[(w * 32 + c * 8) * 64], agl + (size_t)c * 8 * NN + k0);
            async_ld16(&Bs[(w * 32 + c * 8) * 64], bgl + (size_t)c * 8 * NN + k0);
        }
        VM_WAIT(0);
        RAW_BAR();
        __builtin_amdgcn_s_setprio(1);
        #pragma unroll
        for (int kc = 0; kc < 2; ++kc) {
            f16x8 af[4], bf[4];
            #pragma unroll
            for (int t = 0; t < 4; ++t) {
                const int Ra = wr * 64 + t * 16 + m_;
                const int Rb = wc * 64 + t * 16 + m_;
                af[t] = *(const f16x8*)&As[Ra * 64 + (((kc * 4 + quad) ^ (Ra & 7)) * 8)];
                bf[t] = *(const f16x8*)&Bs[Rb * 64 + (((kc * 4 + quad) ^ (Rb & 7)) * 8)];
            }
            #pragma unroll
            for (int i = 0; i < 4; ++i)
                #pragma unroll
                for (int j = 0; j < 4; ++j)
                    acc[i][j] = __builtin_amdgcn_mfma_f32_16x16x32_f16(af[i], bf[j], acc[i][j], 0, 0, 0);
        }
        __builtin_amdgcn_s_setprio(0);
        RAW_BAR();   // all waves done reading before next stage overwrites
    }

    // Epilogue: broadcast reciprocals via LDS, NT stores.
    if (tid < 128) rdI[tid] = 1.0f / dv;
    LGKM_BAR();

    #pragma unroll
    for (int i = 0; i < 4; ++i) {
        const int rowb = wr * 64 + i * 16 + quad * 4;
        #pragma unroll
        for (int r = 0; r < 4; ++r) {
            const float sc = rdI[rowb + r];
            float* op = out + ((size_t)(b * NN + I + rowb + r)) * DD + D0;
            #pragma unroll
            for (int j = 0; j < 4; ++j)
                __builtin_nontemporal_store(acc[i][j][r] * sc,
                                            op + wc * 64 + j * 16 + m_);
        }
    }
}

// ---------------------------------------------------------------------------
extern "C" void kernel_launch(void* const* d_in, const int* in_sizes, int n_in,
                              void* d_out, int out_size, void* d_ws, size_t ws_size,
                              hipStream_t stream) {
    const float* x = (const float*)d_in[0];
    char* ws = (char*)d_ws;
    _Float16* xhn   = (_Float16*)(ws);                        // 32 MiB normalized fp16
    _Float16* vT    = (_Float16*)(ws + (size_t)33554432);     // 32 MiB fp16 x^T
    _Float16* W     = (_Float16*)(ws + (size_t)67108864);     // 128 MiB fp16 exp-scores
    float*    denom = (float*)   (ws + (size_t)201326592);    // 128 KiB
    float*    out   = (float*)d_out;

    k_prep<<<dim3(NN / 64, BB), 256, 0, stream>>>(x, xhn, vT, denom);
    const int npairs = (NN / 128) * (NN / 128 + 1) / 2;   // 136
    k_scores<<<dim3(npairs, 1, BB), 256, 0, stream>>>(xhn, W, denom);
    // 1024 blocks = 4 blocks/CU (32.5 KiB LDS, 4-wave blocks), XCD batch-pinned
    k_pv<<<dim3(1024, 1, 1), 256, 0, stream>>>(W, vT, denom, out);
}